// Round 16
// baseline (792.361 us; speedup 1.0000x reference)
//
#include <hip/hip_runtime.h>
#include <hip/hip_bf16.h>
#include <hip/hip_fp16.h>

#define HDIM 1024
#define BATCH 64
#define SEQ 2048
#define MTOT (BATCH*SEQ)   // 131072
#define BM 128
#define BN 256
#define BK 64
#define NKT (HDIM/BK)      // 16 k-tiles
#define NNT (HDIM/BN)      // 4 n-tiles

typedef float f32x4 __attribute__((ext_vector_type(4)));
typedef _Float16 half8 __attribute__((ext_vector_type(8)));
typedef _Float16 half4v __attribute__((ext_vector_type(4)));

static __device__ __forceinline__ void gload_lds16(const void* g, void* l) {
  __builtin_amdgcn_global_load_lds((const __attribute__((address_space(1))) void*)g,
                                   (__attribute__((address_space(3))) void*)l, 16, 0, 0);
}

// ---------------- kernel 1: W1 [h][k] fp32 -> W1T [k][h] fp16 ----------------
__global__ void k_w1t(const float* __restrict__ W1, unsigned short* __restrict__ W1T) {
  __shared__ float tile[64][65];
  int h0 = blockIdx.x * 64, k0 = blockIdx.y * 64;
  int t = threadIdx.x;
#pragma unroll
  for (int j = 0; j < 4; ++j) {
    int q = j * 256 + t, r = q >> 4, c = (q & 15) * 4;
    float4 v = *(const float4*)(W1 + (size_t)(h0 + r) * HDIM + k0 + c);
    tile[r][c + 0] = v.x; tile[r][c + 1] = v.y; tile[r][c + 2] = v.z; tile[r][c + 3] = v.w;
  }
  __syncthreads();
#pragma unroll
  for (int j = 0; j < 4; ++j) {
    int q = j * 256 + t, r = q >> 4, c = (q & 15) * 4;
    union { _Float16 h[4]; ushort4 u; } cv;
    cv.h[0] = (_Float16)tile[c + 0][r];
    cv.h[1] = (_Float16)tile[c + 1][r];
    cv.h[2] = (_Float16)tile[c + 2][r];
    cv.h[3] = (_Float16)tile[c + 3][r];
    *(ushort4*)(W1T + (size_t)(k0 + r) * HDIM + h0 + c) = cv.u;
  }
}

// ---------------- kernel 2: dec_proj = dh @ W2 + b  (fp32) ----------------
__global__ void k_decproj(const float* __restrict__ dh, const float* __restrict__ W2,
                          const float* __restrict__ W2b, float* __restrict__ dp) {
  __shared__ float drow[HDIM];
  int b = blockIdx.x, t = threadIdx.x;
#pragma unroll
  for (int j = 0; j < 4; ++j) drow[j * 256 + t] = dh[(size_t)b * HDIM + j * 256 + t];
  __syncthreads();
  f32x4 acc = {0.f, 0.f, 0.f, 0.f};
#pragma unroll 16
  for (int h = 0; h < HDIM; ++h) {
    float d = drow[h];
    f32x4 w = *(const f32x4*)(W2 + (size_t)h * HDIM + t * 4);
    acc += w * d;
  }
  acc += *(const f32x4*)(W2b + t * 4);
  *(f32x4*)(dp + (size_t)b * HDIM + t * 4) = acc;
}

// ---------------- kernel 3: fused GEMM + tanh + v-dot, m201-style 8-phase ----------------
// R12/R15 geometry (BM128 x BN256, 512thr/8 waves, wave-tile 64x64) restructured
// into 4 phases per K-tile (m201 template): each phase = {ds_read subtile ||
// stage-issue} -> s_barrier -> lgkmcnt(0)+sched_barrier (rule #18) -> setprio(1)
// -> 8 MFMA -> setprio(0) -> s_barrier. Staging: P1 issues B(kt+1) DMA + A(kt+1)
// reg loads (2 phases of latency cover); P3 cvt->ds_write Ab[nxt] (compiler's
// vmcnt wait on areg drains the OLDER B DMA per-wave -> Bb[nxt] complete before
// P3's closing barrier -> kt+1 reads race-free). Double-buffered LDS 96KB ->
// 1 block/CU; intra-block pipelining replaces TLP (m201's config).
__global__ __launch_bounds__(512, 2) void k_scores(
    const float* __restrict__ E, const unsigned short* __restrict__ W1T,
    const float* __restrict__ W1b, const float* __restrict__ dp,
    const float* __restrict__ vw, float* __restrict__ spart,
    unsigned short* __restrict__ E16, int we16) {
  __shared__ __align__(16) _Float16 Ab[2][BM * BK];        // 2 x 16384 B, swizzled
  __shared__ __align__(16) unsigned short Bb[2][BN * BK];  // 2 x 32768 B, swizzled
  float (*scr)[4] = (float(*)[4])Ab[0];                    // epilogue alias

  int t = threadIdx.x;
  // XCD-aware remap: all 4 n-tiles of an m-tile adjacent on one XCD.
  int bid = blockIdx.x;                 // 0..2047
  int xcd = bid & 7;
  int q = bid >> 3;                     // 0..255
  int mt = (xcd << 7) + (q >> 2);       // hmm: 1024 m-tiles total, 128/XCD
  int nt = q & 3;
  int m0 = mt * BM, n0 = nt * BN;
  int b = m0 >> 11;

  int lane = t & 63, wid = t >> 6;      // 8 waves: wr = row-half, wc = col-quarter
  int wr = wid >> 2, wc = wid & 3;
  int l15 = lane & 15, l4 = lane >> 4;

  f32x4 acc[4][4];
#pragma unroll
  for (int i = 0; i < 4; ++i)
#pragma unroll
    for (int j = 0; j < 4; ++j) acc[i][j] = {0.f, 0.f, 0.f, 0.f};

  // A staging coords: rows j*32+ar (j=0..3), fp32 cols ac..ac+3 ; row&7 == ar&7
  int ar = t >> 4;                       // 0..31
  int ac = (t & 15) * 4;                 // 0..60
  int aswz = (((ac >> 3) ^ (ar & 7)) << 4) + ((ac & 7) << 1);
  const float* Abase = E + (size_t)m0 * HDIM;

  // B staging coords (4 chunks of 1KB per wave, pre-swizzled source)
  int brow_in = lane >> 3;
  int bu = (lane & 7) ^ brow_in;

  float4 areg[4];
  // ---- prologue: B(0) -> Bb[0]; A(0) -> regs -> cvt -> Ab[0] (+E16 slice)
#pragma unroll
  for (int j = 0; j < 4; ++j) {
    int chunk = wid * 4 + j;
    int row = chunk * 8 + brow_in;
    gload_lds16(W1T + (size_t)(n0 + row) * HDIM + bu * 8, (char*)Bb[0] + (size_t)chunk * 1024);
  }
#pragma unroll
  for (int j = 0; j < 4; ++j)
    areg[j] = *(const float4*)(Abase + (size_t)(j * 32 + ar) * HDIM + ac);
#pragma unroll
  for (int j = 0; j < 4; ++j) {
    union { _Float16 h[4]; unsigned long long u64; } cv;
    cv.h[0] = (_Float16)areg[j].x; cv.h[1] = (_Float16)areg[j].y;
    cv.h[2] = (_Float16)areg[j].z; cv.h[3] = (_Float16)areg[j].w;
    *(unsigned long long*)((char*)Ab[0] + (j * 32 + ar) * 128 + aswz) = cv.u64;
    if (we16 && j == nt)
      __builtin_nontemporal_store(cv.u64,
          (unsigned long long*)(E16 + (size_t)(m0 + j * 32 + ar) * HDIM + ac));
  }
  __syncthreads();

  for (int kt = 0; kt < NKT; ++kt) {
    const char* Ac = (const char*)Ab[kt & 1];
    const char* Bc = (const char*)Bb[kt & 1];
    char* Bd = (char*)Bb[(kt + 1) & 1];
    char* Ad = (char*)Ab[(kt + 1) & 1];
    bool pf = (kt + 1 < NKT);
    int ktn = (kt + 1) * BK;             // only used when pf
    half8 af[4], bf0, bf1;

    // ================ P1: ks0, ni0-1 ; stage-issue B(kt+1) + A(kt+1) ================
#pragma unroll
    for (int mi = 0; mi < 4; ++mi) {
      int row = wr * 64 + mi * 16 + l15;
      af[mi] = *(const half8*)(Ac + row * 128 + ((l4 ^ (row & 7)) << 4));
    }
    {
      int r0 = wc * 64 + l15;
      bf0 = *(const half8*)(Bc + r0 * 128 + ((l4 ^ (r0 & 7)) << 4));
      int r1 = wc * 64 + 16 + l15;
      bf1 = *(const half8*)(Bc + r1 * 128 + ((l4 ^ (r1 & 7)) << 4));
    }
    if (pf) {
#pragma unroll
      for (int j = 0; j < 4; ++j) {
        int chunk = wid * 4 + j;
        int row = chunk * 8 + brow_in;
        gload_lds16(W1T + (size_t)(n0 + row) * HDIM + ktn + bu * 8, Bd + (size_t)chunk * 1024);
      }
#pragma unroll
      for (int j = 0; j < 4; ++j)
        areg[j] = *(const float4*)(Abase + (size_t)(j * 32 + ar) * HDIM + ktn + ac);
    }
    __builtin_amdgcn_s_barrier();
    asm volatile("s_waitcnt lgkmcnt(0)" ::: "memory");
    __builtin_amdgcn_sched_barrier(0);
    __builtin_amdgcn_s_setprio(1);
#pragma unroll
    for (int mi = 0; mi < 4; ++mi) {
      acc[mi][0] = __builtin_amdgcn_mfma_f32_16x16x32_f16(af[mi], bf0, acc[mi][0], 0, 0, 0);
      acc[mi][1] = __builtin_amdgcn_mfma_f32_16x16x32_f16(af[mi], bf1, acc[mi][1], 0, 0, 0);
    }
    __builtin_amdgcn_s_setprio(0);
    __builtin_amdgcn_s_barrier();

    // ================ P2: ks0, ni2-3 (light) ================
    {
      int r0 = wc * 64 + 32 + l15;
      bf0 = *(const half8*)(Bc + r0 * 128 + ((l4 ^ (r0 & 7)) << 4));
      int r1 = wc * 64 + 48 + l15;
      bf1 = *(const half8*)(Bc + r1 * 128 + ((l4 ^ (r1 & 7)) << 4));
    }
    __builtin_amdgcn_s_barrier();
    asm volatile("s_waitcnt lgkmcnt(0)" ::: "memory");
    __builtin_amdgcn_sched_barrier(0);
    __builtin_amdgcn_s_setprio(1);
#pragma unroll
    for (int mi = 0; mi < 4; ++mi) {
      acc[mi][2] = __builtin_amdgcn_mfma_f32_16x16x32_f16(af[mi], bf0, acc[mi][2], 0, 0, 0);
      acc[mi][3] = __builtin_amdgcn_mfma_f32_16x16x32_f16(af[mi], bf1, acc[mi][3], 0, 0, 0);
    }
    __builtin_amdgcn_s_setprio(0);
    __builtin_amdgcn_s_barrier();

    // ================ P3: ks1, ni0-1 ; cvt A(kt+1) -> Ab[nxt] (+E16) ================
#pragma unroll
    for (int mi = 0; mi < 4; ++mi) {
      int row = wr * 64 + mi * 16 + l15;
      af[mi] = *(const half8*)(Ac + row * 128 + (((4 + l4) ^ (row & 7)) << 4));
    }
    {
      int r0 = wc * 64 + l15;
      bf0 = *(const half8*)(Bc + r0 * 128 + (((4 + l4) ^ (r0 & 7)) << 4));
      int r1 = wc * 64 + 16 + l15;
      bf1 = *(const half8*)(Bc + r1 * 128 + (((4 + l4) ^ (r1 & 7)) << 4));
    }
    if (pf) {
      // compiler emits the counted vmcnt wait for areg here; since the B DMA
      // (same phase-1 issue, older) retires first, Bb[nxt] is complete for this
      // wave before its P3 closing barrier -> kt+1 reads are race-free.
#pragma unroll
      for (int j = 0; j < 4; ++j) {
        union { _Float16 h[4]; unsigned long long u64; } cv;
        cv.h[0] = (_Float16)areg[j].x; cv.h[1] = (_Float16)areg[j].y;
        cv.h[2] = (_Float16)areg[j].z; cv.h[3] = (_Float16)areg[j].w;
        *(unsigned long long*)(Ad + (j * 32 + ar) * 128 + aswz) = cv.u64;
        if (we16 && j == nt)
          __builtin_nontemporal_store(cv.u64,
              (unsigned long long*)(E16 + (size_t)(m0 + j * 32 + ar) * HDIM + ktn + ac));
      }
    }
    __builtin_amdgcn_s_barrier();
    asm volatile("s_waitcnt lgkmcnt(0)" ::: "memory");
    __builtin_amdgcn_sched_barrier(0);
    __builtin_amdgcn_s_setprio(1);
#pragma unroll
    for (int mi = 0; mi < 4; ++mi) {
      acc[mi][0] = __builtin_amdgcn_mfma_f32_16x16x32_f16(af[mi], bf0, acc[mi][0], 0, 0, 0);
      acc[mi][1] = __builtin_amdgcn_mfma_f32_16x16x32_f16(af[mi], bf1, acc[mi][1], 0, 0, 0);
    }
    __builtin_amdgcn_s_setprio(0);
    __builtin_amdgcn_s_barrier();

    // ================ P4: ks1, ni2-3 (light) ================
    {
      int r0 = wc * 64 + 32 + l15;
      bf0 = *(const half8*)(Bc + r0 * 128 + (((4 + l4) ^ (r0 & 7)) << 4));
      int r1 = wc * 64 + 48 + l15;
      bf1 = *(const half8*)(Bc + r1 * 128 + (((4 + l4) ^ (r1 & 7)) << 4));
    }
    __builtin_amdgcn_s_barrier();
    asm volatile("s_waitcnt lgkmcnt(0)" ::: "memory");
    __builtin_amdgcn_sched_barrier(0);
    __builtin_amdgcn_s_setprio(1);
#pragma unroll
    for (int mi = 0; mi < 4; ++mi) {
      acc[mi][2] = __builtin_amdgcn_mfma_f32_16x16x32_f16(af[mi], bf0, acc[mi][2], 0, 0, 0);
      acc[mi][3] = __builtin_amdgcn_mfma_f32_16x16x32_f16(af[mi], bf1, acc[mi][3], 0, 0, 0);
    }
    __builtin_amdgcn_s_setprio(0);
    __builtin_amdgcn_s_barrier();
  }

  // epilogue: bias/v loads (VGPR headroom during loop), tanh + v-dot, reduce
  float bias_l[4], v_l[4];
#pragma unroll
  for (int ni = 0; ni < 4; ++ni) {
    int k = n0 + wc * 64 + ni * 16 + l15;
    bias_l[ni] = W1b[k] + dp[(size_t)b * HDIM + k];
    v_l[ni] = vw[k];
  }
#pragma unroll
  for (int mi = 0; mi < 4; ++mi) {
#pragma unroll
    for (int r = 0; r < 4; ++r) {
      float s = 0.f;
#pragma unroll
      for (int ni = 0; ni < 4; ++ni) {
        float x = acc[mi][ni][r] + bias_l[ni];
        float ex = __expf(2.f * x);
        float th = 1.f - 2.f / (ex + 1.f);
        s += th * v_l[ni];
      }
      s += __shfl_xor(s, 1); s += __shfl_xor(s, 2);
      s += __shfl_xor(s, 4); s += __shfl_xor(s, 8);
      if (l15 == 0) scr[wr * 64 + mi * 16 + l4 * 4 + r][wc] = s;
    }
  }
  __syncthreads();
  if (t < BM) {
    f32x4 p = *(const f32x4*)scr[t];
    spart[((size_t)m0 + t) * NNT + nt] = (p[0] + p[1]) + (p[2] + p[3]);
  }
}

// ---------------- kernel 4: softmax over S per batch ----------------
__global__ void k_softmax(const float* __restrict__ spart, float* __restrict__ attn) {
  __shared__ float sc[SEQ];
  __shared__ float red[8];
  int b = blockIdx.x, t = threadIdx.x;
  float mx = -1e30f;
#pragma unroll
  for (int j = 0; j < 8; ++j) {
    int s = j * 256 + t;
    f32x4 x = *(const f32x4*)(spart + ((size_t)b * SEQ + s) * NNT);
    float v = (x[0] + x[1]) + (x[2] + x[3]);
    sc[s] = v;
    mx = fmaxf(mx, v);
  }
  for (int m = 1; m < 64; m <<= 1) mx = fmaxf(mx, __shfl_xor(mx, m));
  if ((t & 63) == 0) red[t >> 6] = mx;
  __syncthreads();
  mx = fmaxf(fmaxf(red[0], red[1]), fmaxf(red[2], red[3]));
  float w[8]; float sum = 0.f;
#pragma unroll
  for (int j = 0; j < 8; ++j) {
    float e = __expf(sc[j * 256 + t] - mx);
    w[j] = e; sum += e;
  }
  for (int m = 1; m < 64; m <<= 1) sum += __shfl_xor(sum, m);
  if ((t & 63) == 0) red[4 + (t >> 6)] = sum;
  __syncthreads();
  float inv = 1.f / (red[4] + red[5] + red[6] + red[7]);
#pragma unroll
  for (int j = 0; j < 8; ++j)
    attn[(size_t)b * SEQ + j * 256 + t] = w[j] * inv;
}

// ---------------- kernel 5a: context partials, fp32 E (fallback) ----------------
__global__ void k_ctx_part(const float* __restrict__ E, const float* __restrict__ attn,
                           float* __restrict__ cpart, int rpc) {
  int b = blockIdx.y, ch = blockIdx.x, nch = gridDim.x;
  int t = threadIdx.x;
  const float* wrow = attn + (size_t)b * SEQ + (size_t)ch * rpc;
  const float* Eb = E + ((size_t)b * SEQ + (size_t)ch * rpc) * HDIM;
  f32x4 acc = {0.f, 0.f, 0.f, 0.f};
#pragma unroll 4
  for (int s = 0; s < rpc; ++s) {
    float w = wrow[s];
    f32x4 e = *(const f32x4*)(Eb + (size_t)s * HDIM + t * 4);
    acc += e * w;
  }
  *(f32x4*)(cpart + ((size_t)b * nch + ch) * HDIM + t * 4) = acc;
}

// ---------------- kernel 5b: context partials, fp16 E mirror ----------------
__global__ void k_ctx_part16(const unsigned short* __restrict__ E16, const float* __restrict__ attn,
                             float* __restrict__ cpart, int rpc) {
  int b = blockIdx.y, ch = blockIdx.x, nch = gridDim.x;
  int t = threadIdx.x;
  const float* wrow = attn + (size_t)b * SEQ + (size_t)ch * rpc;
  const unsigned short* Eb = E16 + ((size_t)b * SEQ + (size_t)ch * rpc) * HDIM;
  f32x4 acc = {0.f, 0.f, 0.f, 0.f};
#pragma unroll 4
  for (int s = 0; s < rpc; ++s) {
    float w = wrow[s];
    half4v e = *(const half4v*)(Eb + (size_t)s * HDIM + t * 4);
    acc[0] += w * (float)e[0];
    acc[1] += w * (float)e[1];
    acc[2] += w * (float)e[2];
    acc[3] += w * (float)e[3];
  }
  *(f32x4*)(cpart + ((size_t)b * nch + ch) * HDIM + t * 4) = acc;
}

// ---------------- kernel 6: reduce context partials ----------------
__global__ void k_ctx_reduce(const float* __restrict__ cpart, float* __restrict__ ctx, int nch) {
  int idx = blockIdx.x * 256 + threadIdx.x;  // 0..65535
  int b = idx >> 10, k = idx & 1023;
  float s = 0.f;
  for (int c = 0; c < nch; ++c) s += cpart[((size_t)(b * nch + c)) * HDIM + k];
  ctx[idx] = s;
}

extern "C" void kernel_launch(void* const* d_in, const int* in_sizes, int n_in,
                              void* d_out, int out_size, void* d_ws, size_t ws_size,
                              hipStream_t stream) {
  const float* dh  = (const float*)d_in[0];
  const float* E   = (const float*)d_in[1];
  const float* W1w = (const float*)d_in[2];
  const float* W1b = (const float*)d_in[3];
  const float* W2w = (const float*)d_in[4];
  const float* W2b = (const float*)d_in[5];
  const float* vw  = (const float*)d_in[6];
  float* out  = (float*)d_out;
  float* ctx  = out;                 // [64,1024]
  float* attn = out + BATCH * HDIM;  // [64,2048]

  char* ws = (char*)d_ws;
  unsigned short* W1T = (unsigned short*)ws;                 // 2 MB
  float* dp    = (float*)(ws + (2u << 20));                  // 256 KB
  float* spart = (float*)(ws + (2u << 20) + (256u << 10));   // 2 MB used (4 MB reserved)
  float* cpart = (float*)(ws + (6u << 20) + (256u << 10));   // up to 8 MB
  unsigned short* E16 = (unsigned short*)(ws + (14u << 20) + (256u << 10));  // 256 MB if it fits

  size_t need32  = (6u << 20) + (256u << 10) + (size_t)BATCH * 32 * HDIM * 4;
  size_t needE16 = (14u << 20) + (256u << 10) + (size_t)MTOT * HDIM * 2;
  int nch = (ws_size >= need32) ? 32 : 16;
  int rpc = SEQ / nch;
  int use16 = (ws_size >= needE16) ? 1 : 0;

  k_w1t<<<dim3(16, 16), 256, 0, stream>>>(W1w, W1T);
  k_decproj<<<BATCH, 256, 0, stream>>>(dh, W2w, W2b, dp);
  k_scores<<<(MTOT / BM) * NNT, 512, 0, stream>>>(E, W1T, W1b, dp, vw, spart,
                                                  use16 ? E16 : W1T, use16);
  k_softmax<<<BATCH, 256, 0, stream>>>(spart, attn);
  if (use16)
    k_ctx_part16<<<dim3(nch, BATCH), 256, 0, stream>>>(E16, attn, cpart, rpc);
  else
    k_ctx_part<<<dim3(nch, BATCH), 256, 0, stream>>>(E, attn, cpart, rpc);
  k_ctx_reduce<<<256, 256, 0, stream>>>(cpart, ctx, nch);
}

// Round 17
// 502.940 us; speedup vs baseline: 1.5755x; 1.5755x over previous
//
#include <hip/hip_runtime.h>
#include <hip/hip_bf16.h>
#include <hip/hip_fp16.h>

#define HDIM 1024
#define BATCH 64
#define SEQ 2048
#define MTOT (BATCH*SEQ)   // 131072
#define BM 128
#define BN 256
#define BK 64
#define NKT (HDIM/BK)      // 16 k-tiles
#define NNT (HDIM/BN)      // 4 n-tiles

typedef float f32x4 __attribute__((ext_vector_type(4)));
typedef _Float16 half8 __attribute__((ext_vector_type(8)));
typedef _Float16 half4v __attribute__((ext_vector_type(4)));

static __device__ __forceinline__ void gload_lds16(const void* g, void* l) {
  __builtin_amdgcn_global_load_lds((const __attribute__((address_space(1))) void*)g,
                                   (__attribute__((address_space(3))) void*)l, 16, 0, 0);
}

// ---------------- kernel 1: W1 [h][k] fp32 -> W1T [k][h] fp16 ----------------
__global__ void k_w1t(const float* __restrict__ W1, unsigned short* __restrict__ W1T) {
  __shared__ float tile[64][65];
  int h0 = blockIdx.x * 64, k0 = blockIdx.y * 64;
  int t = threadIdx.x;
#pragma unroll
  for (int j = 0; j < 4; ++j) {
    int q = j * 256 + t, r = q >> 4, c = (q & 15) * 4;
    float4 v = *(const float4*)(W1 + (size_t)(h0 + r) * HDIM + k0 + c);
    tile[r][c + 0] = v.x; tile[r][c + 1] = v.y; tile[r][c + 2] = v.z; tile[r][c + 3] = v.w;
  }
  __syncthreads();
#pragma unroll
  for (int j = 0; j < 4; ++j) {
    int q = j * 256 + t, r = q >> 4, c = (q & 15) * 4;
    union { _Float16 h[4]; ushort4 u; } cv;
    cv.h[0] = (_Float16)tile[c + 0][r];
    cv.h[1] = (_Float16)tile[c + 1][r];
    cv.h[2] = (_Float16)tile[c + 2][r];
    cv.h[3] = (_Float16)tile[c + 3][r];
    *(ushort4*)(W1T + (size_t)(k0 + r) * HDIM + h0 + c) = cv.u;
  }
}

// ---------------- kernel 2: dec_proj = dh @ W2 + b  (fp32) ----------------
__global__ void k_decproj(const float* __restrict__ dh, const float* __restrict__ W2,
                          const float* __restrict__ W2b, float* __restrict__ dp) {
  __shared__ float drow[HDIM];
  int b = blockIdx.x, t = threadIdx.x;
#pragma unroll
  for (int j = 0; j < 4; ++j) drow[j * 256 + t] = dh[(size_t)b * HDIM + j * 256 + t];
  __syncthreads();
  f32x4 acc = {0.f, 0.f, 0.f, 0.f};
#pragma unroll 16
  for (int h = 0; h < HDIM; ++h) {
    float d = drow[h];
    f32x4 w = *(const f32x4*)(W2 + (size_t)h * HDIM + t * 4);
    acc += w * d;
  }
  acc += *(const f32x4*)(W2b + t * 4);
  *(f32x4*)(dp + (size_t)b * HDIM + t * 4) = acc;
}

// ---------------- kernel 3: fused GEMM + tanh + v-dot -> score partials ----------------
// R15 core (R12's verified 2-phase loop + balanced E16 side-write) with ONE
// change: the E16 nontemporal store is issued AFTER barrier #1 (value held in
// a register), so its ack drains at barrier #2 — a full MFMA phase later —
// instead of stalling barrier #1 ~50cyc after issue. 8-phase port (R16) hit
// the m232 regime-gate null at this tile shape; scheduling work is closed.
__global__ __launch_bounds__(512, 4) void k_scores(
    const float* __restrict__ E, const unsigned short* __restrict__ W1T,
    const float* __restrict__ W1b, const float* __restrict__ dp,
    const float* __restrict__ vw, float* __restrict__ spart,
    unsigned short* __restrict__ E16, int we16) {
  __shared__ __align__(16) _Float16 As[BM * BK];         // 16384 B, swizzled
  __shared__ __align__(16) unsigned short Bs[BN * BK];   // 32768 B, swizzled
  float (*scr)[4] = (float(*)[4])As;                     // epilogue alias (post-barrier safe)

  int t = threadIdx.x;
  // XCD-aware remap: all 4 n-tiles of an m-tile adjacent on one XCD.
  int bid = blockIdx.x;                 // 0..4095
  int xcd = bid & 7;
  int q = bid >> 3;                     // 0..511
  int mt = (xcd << 7) + (q >> 2);       // 128 m-tiles per XCD
  int nt = q & 3;
  int m0 = mt * BM, n0 = nt * BN;
  int b = m0 >> 11;

  int lane = t & 63, wid = t >> 6;      // 8 waves: wr = row-half, wc = col-quarter
  int wr = wid >> 2, wc = wid & 3;
  int l15 = lane & 15, l4 = lane >> 4;

  f32x4 acc[4][4];
#pragma unroll
  for (int i = 0; i < 4; ++i)
#pragma unroll
    for (int j = 0; j < 4; ++j) acc[i][j] = {0.f, 0.f, 0.f, 0.f};

  // A staging coords: 512 thr cover 128x64 fp32 as 4 float4/thread.
  int ar = t >> 4;                       // 0..31 ; row&7 == ar&7
  int ac = (t & 15) * 4;                 // 0..60
  int aswz = (((ac >> 3) ^ (ar & 7)) << 4) + ((ac & 7) << 1);
  const float* Ab = E + (size_t)m0 * HDIM;
  unsigned short* e16p = E16 + (size_t)(m0 + nt * 32 + ar) * HDIM + ac;  // this block's slice

  // prologue: A(0) -> regs
  float4 areg[4];
#pragma unroll
  for (int j = 0; j < 4; ++j)
    areg[j] = *(const float4*)(Ab + (size_t)(j * 32 + ar) * HDIM + ac);

  for (int kt = 0; kt < NKT; ++kt) {
    // (1) issue B(kt): 4 gload_lds per wave (32 chunks of 1KB), pre-swizzled src.
#pragma unroll
    for (int j = 0; j < 4; ++j) {
      int chunk = wid * 4 + j;                     // 0..31 (wave-uniform)
      int row = chunk * 8 + (lane >> 3);           // 0..255 ; row&7 == lane>>3
      int u = (lane & 7) ^ (lane >> 3);
      const unsigned short* g = W1T + (size_t)(n0 + row) * HDIM + kt * BK + u * 8;
      gload_lds16(g, (char*)Bs + (size_t)chunk * 1024);
    }

    // (2) cvt A(kt) regs -> fp16 -> swizzled LDS; capture j==nt slice in a reg
    unsigned long long e16v = 0;
#pragma unroll
    for (int j = 0; j < 4; ++j) {
      union { _Float16 h[4]; unsigned long long u64; } cv;
      cv.h[0] = (_Float16)areg[j].x; cv.h[1] = (_Float16)areg[j].y;
      cv.h[2] = (_Float16)areg[j].z; cv.h[3] = (_Float16)areg[j].w;
      *(unsigned long long*)((char*)As + (j * 32 + ar) * 128 + aswz) = cv.u64;
      if (j == nt) e16v = cv.u64;
    }

    __syncthreads();   // drains B gloads + A ds_writes (no store ack here now)

    // (3) E16 store issued HERE: ack drains at barrier #2, covered by the MFMA
    //     phase (~600+ cyc). Nontemporal -> no L2 eviction of the working set.
    if (we16)
      __builtin_nontemporal_store(e16v, (unsigned long long*)(e16p + kt * BK));

    //     prefetch A(kt+1) -> regs; latency hides under MFMA below
    int ktn = ((kt + 1) & (NKT - 1)) * BK;
#pragma unroll
    for (int j = 0; j < 4; ++j)
      areg[j] = *(const float4*)(Ab + (size_t)(j * 32 + ar) * HDIM + ktn + ac);

    // (4) fragments + MFMA (swizzled reads: 0 conflicts)
    __builtin_amdgcn_s_setprio(1);
#pragma unroll
    for (int ks = 0; ks < 2; ++ks) {
      half8 af[4], bf[4];
#pragma unroll
      for (int mi = 0; mi < 4; ++mi) {
        int row = wr * 64 + mi * 16 + l15;
        af[mi] = *(const half8*)((const char*)As + row * 128 + (((ks * 4 + l4) ^ (row & 7)) << 4));
      }
#pragma unroll
      for (int ni = 0; ni < 4; ++ni) {
        int row = wc * 64 + ni * 16 + l15;
        bf[ni] = *(const half8*)((const char*)Bs + row * 128 + (((ks * 4 + l4) ^ (row & 7)) << 4));
      }
#pragma unroll
      for (int mi = 0; mi < 4; ++mi)
#pragma unroll
        for (int ni = 0; ni < 4; ++ni)
          acc[mi][ni] = __builtin_amdgcn_mfma_f32_16x16x32_f16(af[mi], bf[ni], acc[mi][ni], 0, 0, 0);
    }
    __builtin_amdgcn_s_setprio(0);

    __syncthreads();   // LDS reads done before next iter overwrites
  }

  // epilogue: bias/v loaded here (VGPR headroom during loop)
  float bias_l[4], v_l[4];
#pragma unroll
  for (int ni = 0; ni < 4; ++ni) {
    int k = n0 + wc * 64 + ni * 16 + l15;
    bias_l[ni] = W1b[k] + dp[(size_t)b * HDIM + k];
    v_l[ni] = vw[k];
  }
#pragma unroll
  for (int mi = 0; mi < 4; ++mi) {
#pragma unroll
    for (int r = 0; r < 4; ++r) {
      float s = 0.f;
#pragma unroll
      for (int ni = 0; ni < 4; ++ni) {
        float x = acc[mi][ni][r] + bias_l[ni];
        float ex = __expf(2.f * x);
        float th = 1.f - 2.f / (ex + 1.f);
        s += th * v_l[ni];
      }
      s += __shfl_xor(s, 1); s += __shfl_xor(s, 2);
      s += __shfl_xor(s, 4); s += __shfl_xor(s, 8);
      if (l15 == 0) scr[wr * 64 + mi * 16 + l4 * 4 + r][wc] = s;
    }
  }
  __syncthreads();
  if (t < BM) {
    f32x4 p = *(const f32x4*)scr[t];
    spart[((size_t)m0 + t) * NNT + nt] = (p[0] + p[1]) + (p[2] + p[3]);
  }
}

// ---------------- kernel 4: softmax over S per batch ----------------
__global__ void k_softmax(const float* __restrict__ spart, float* __restrict__ attn) {
  __shared__ float sc[SEQ];
  __shared__ float red[8];
  int b = blockIdx.x, t = threadIdx.x;
  float mx = -1e30f;
#pragma unroll
  for (int j = 0; j < 8; ++j) {
    int s = j * 256 + t;
    f32x4 x = *(const f32x4*)(spart + ((size_t)b * SEQ + s) * NNT);
    float v = (x[0] + x[1]) + (x[2] + x[3]);
    sc[s] = v;
    mx = fmaxf(mx, v);
  }
  for (int m = 1; m < 64; m <<= 1) mx = fmaxf(mx, __shfl_xor(mx, m));
  if ((t & 63) == 0) red[t >> 6] = mx;
  __syncthreads();
  mx = fmaxf(fmaxf(red[0], red[1]), fmaxf(red[2], red[3]));
  float w[8]; float sum = 0.f;
#pragma unroll
  for (int j = 0; j < 8; ++j) {
    float e = __expf(sc[j * 256 + t] - mx);
    w[j] = e; sum += e;
  }
  for (int m = 1; m < 64; m <<= 1) sum += __shfl_xor(sum, m);
  if ((t & 63) == 0) red[4 + (t >> 6)] = sum;
  __syncthreads();
  float inv = 1.f / (red[4] + red[5] + red[6] + red[7]);
#pragma unroll
  for (int j = 0; j < 8; ++j)
    attn[(size_t)b * SEQ + j * 256 + t] = w[j] * inv;
}

// ---------------- kernel 5a: context partials, fp32 E (fallback) ----------------
__global__ void k_ctx_part(const float* __restrict__ E, const float* __restrict__ attn,
                           float* __restrict__ cpart, int rpc) {
  int b = blockIdx.y, ch = blockIdx.x, nch = gridDim.x;
  int t = threadIdx.x;
  const float* wrow = attn + (size_t)b * SEQ + (size_t)ch * rpc;
  const float* Eb = E + ((size_t)b * SEQ + (size_t)ch * rpc) * HDIM;
  f32x4 acc = {0.f, 0.f, 0.f, 0.f};
#pragma unroll 4
  for (int s = 0; s < rpc; ++s) {
    float w = wrow[s];
    f32x4 e = *(const f32x4*)(Eb + (size_t)s * HDIM + t * 4);
    acc += e * w;
  }
  *(f32x4*)(cpart + ((size_t)b * nch + ch) * HDIM + t * 4) = acc;
}

// ---------------- kernel 5b: context partials, fp16 E mirror (half the bytes) ----------------
__global__ void k_ctx_part16(const unsigned short* __restrict__ E16, const float* __restrict__ attn,
                             float* __restrict__ cpart, int rpc) {
  int b = blockIdx.y, ch = blockIdx.x, nch = gridDim.x;
  int t = threadIdx.x;
  const float* wrow = attn + (size_t)b * SEQ + (size_t)ch * rpc;
  const unsigned short* Eb = E16 + ((size_t)b * SEQ + (size_t)ch * rpc) * HDIM;
  f32x4 acc = {0.f, 0.f, 0.f, 0.f};
#pragma unroll 4
  for (int s = 0; s < rpc; ++s) {
    float w = wrow[s];
    half4v e = *(const half4v*)(Eb + (size_t)s * HDIM + t * 4);
    acc[0] += w * (float)e[0];
    acc[1] += w * (float)e[1];
    acc[2] += w * (float)e[2];
    acc[3] += w * (float)e[3];
  }
  *(f32x4*)(cpart + ((size_t)b * nch + ch) * HDIM + t * 4) = acc;
}

// ---------------- kernel 6: reduce context partials ----------------
__global__ void k_ctx_reduce(const float* __restrict__ cpart, float* __restrict__ ctx, int nch) {
  int idx = blockIdx.x * 256 + threadIdx.x;  // 0..65535
  int b = idx >> 10, k = idx & 1023;
  float s = 0.f;
  for (int c = 0; c < nch; ++c) s += cpart[((size_t)(b * nch + c)) * HDIM + k];
  ctx[idx] = s;
}

extern "C" void kernel_launch(void* const* d_in, const int* in_sizes, int n_in,
                              void* d_out, int out_size, void* d_ws, size_t ws_size,
                              hipStream_t stream) {
  const float* dh  = (const float*)d_in[0];
  const float* E   = (const float*)d_in[1];
  const float* W1w = (const float*)d_in[2];
  const float* W1b = (const float*)d_in[3];
  const float* W2w = (const float*)d_in[4];
  const float* W2b = (const float*)d_in[5];
  const float* vw  = (const float*)d_in[6];
  float* out  = (float*)d_out;
  float* ctx  = out;                 // [64,1024]
  float* attn = out + BATCH * HDIM;  // [64,2048]

  char* ws = (char*)d_ws;
  unsigned short* W1T = (unsigned short*)ws;                 // 2 MB
  float* dp    = (float*)(ws + (2u << 20));                  // 256 KB
  float* spart = (float*)(ws + (2u << 20) + (256u << 10));   // 2 MB used (4 MB reserved)
  float* cpart = (float*)(ws + (6u << 20) + (256u << 10));   // up to 8 MB
  unsigned short* E16 = (unsigned short*)(ws + (14u << 20) + (256u << 10));  // 256 MB if it fits

  size_t need32  = (6u << 20) + (256u << 10) + (size_t)BATCH * 32 * HDIM * 4;
  size_t needE16 = (14u << 20) + (256u << 10) + (size_t)MTOT * HDIM * 2;
  int nch = (ws_size >= need32) ? 32 : 16;
  int rpc = SEQ / nch;
  int use16 = (ws_size >= needE16) ? 1 : 0;

  k_w1t<<<dim3(16, 16), 256, 0, stream>>>(W1w, W1T);
  k_decproj<<<BATCH, 256, 0, stream>>>(dh, W2w, W2b, dp);
  k_scores<<<(MTOT / BM) * NNT, 512, 0, stream>>>(E, W1T, W1b, dp, vw, spart,
                                                  use16 ? E16 : W1T, use16);
  k_softmax<<<BATCH, 256, 0, stream>>>(spart, attn);
  if (use16)
    k_ctx_part16<<<dim3(nch, BATCH), 256, 0, stream>>>(E16, attn, cpart, rpc);
  else
    k_ctx_part<<<dim3(nch, BATCH), 256, 0, stream>>>(E, attn, cpart, rpc);
  k_ctx_reduce<<<256, 256, 0, stream>>>(cpart, ctx, nch);
}